// Round 5
// baseline (215.091 us; speedup 1.0000x reference)
//
#include <hip/hip_runtime.h>
#include <hip/hip_bf16.h>

// MoE: N=8192 tokens, D=1024, E=8 experts, top-2 routing.
// Inputs (fp32): x[8192,1024], Wr[1024,8], br[8], W[8,1024,1024], b[8,1024]
// Output (fp32): out[8192,1024]
//
// R1: block-aggregated scatter (router atomics 16384 -> 128).
// R2: dense tile list. R3: split-K regressed (epilogue-dominated).
// R4: atomic-free epilogue (bf16 ybuf + combine pass), eff. BK=64.
// R5: GEMM LDS 33280->32768 (5 blocks/CU, sTok/sGate removed), slot-major
//     block order (B-tile L2 reuse); transpose rewritten (512B coalesced
//     writes, vectorized LDS).

#define NTOK 8192
#define DM   1024
#define NEXP 8
#define CAP  8192    // per-expert slot capacity (worst case)
#define MAXT 136     // max total m-tiles

typedef __attribute__((ext_vector_type(8))) short bf16x8;
typedef __attribute__((ext_vector_type(4))) float f32x4;

__device__ __forceinline__ unsigned short f2bf(float f) {
  unsigned u = __float_as_uint(f);
  unsigned r = (u + 0x7fffu + ((u >> 16) & 1u)) >> 16;
  return (unsigned short)r;
}
__device__ __forceinline__ float bf2f(unsigned short s) {
  return __uint_as_float(((unsigned)s) << 16);
}

__device__ __forceinline__ void gl_lds16(const void* g, void* l) {
  __builtin_amdgcn_global_load_lds(
      (const __attribute__((address_space(1))) unsigned int*)g,
      (__attribute__((address_space(3))) unsigned int*)l, 16, 0, 0);
}

// ---------------- W transpose + bf16 cast: Wt[e][h][d] = bf16(W[e][d][h]) ---
// Block: d in [d0,d0+256), h in [h0,h0+64). Reads 256B segments, writes 512B
// contiguous per wave. LDS pad 260 keeps ushort4 8B-aligned.
__global__ __launch_bounds__(256) void transpose_w_kernel(
    const float* __restrict__ W, unsigned short* __restrict__ Wt) {
  __shared__ unsigned short L[64 * 260];  // L[h][d]
  const int e = blockIdx.z;
  const int d0 = blockIdx.y * 256, h0 = blockIdx.x * 64;
  const float* Ws = W + (size_t)e * DM * DM;
  unsigned short* Wd = Wt + (size_t)e * DM * DM;
  const int tid = threadIdx.x;
  const int hh = (tid & 15) * 4;  // 0..60
  const int dr = tid >> 4;        // 0..15
#pragma unroll
  for (int it = 0; it < 16; it++) {
    int dd = it * 16 + dr;
    float4 v = *(const float4*)(Ws + (size_t)(d0 + dd) * DM + h0 + hh);
    L[(hh + 0) * 260 + dd] = f2bf(v.x);
    L[(hh + 1) * 260 + dd] = f2bf(v.y);
    L[(hh + 2) * 260 + dd] = f2bf(v.z);
    L[(hh + 3) * 260 + dd] = f2bf(v.w);
  }
  __syncthreads();
  const int dc = (tid & 63) * 4;  // 0..252
  const int hw = tid >> 6;        // 0..3
#pragma unroll
  for (int it = 0; it < 16; it++) {
    int hr = it * 4 + hw;
    ushort4 o = *(const ushort4*)(&L[hr * 260 + dc]);
    *(ushort4*)(Wd + (size_t)(h0 + hr) * DM + d0 + dc) = o;
  }
}

// ---------------- Router compute: fp32 logits, top-2, gates (atomic-free) ---
__global__ __launch_bounds__(256) void router_compute_kernel(
    const float* __restrict__ x, const float* __restrict__ Wr,
    const float* __restrict__ br, unsigned short* __restrict__ xbf,
    int4* __restrict__ topk) {
  const int tid = threadIdx.x;
  const int wave = tid >> 6, lane = tid & 63;
  const int t = blockIdx.x * 4 + wave;
  const int c0 = lane * 16;
  const float* xr = x + (size_t)t * DM + c0;

  float v[16];
#pragma unroll
  for (int i = 0; i < 4; i++) {
    float4 f = *(const float4*)(xr + i * 4);
    v[i * 4 + 0] = f.x; v[i * 4 + 1] = f.y; v[i * 4 + 2] = f.z; v[i * 4 + 3] = f.w;
  }
  union { unsigned short s[8]; uint4 q; } pk;
#pragma unroll
  for (int half = 0; half < 2; half++) {
#pragma unroll
    for (int i = 0; i < 8; i++) pk.s[i] = f2bf(v[half * 8 + i]);
    *(uint4*)(xbf + (size_t)t * DM + c0 + half * 8) = pk.q;
  }
  float p[8] = {0, 0, 0, 0, 0, 0, 0, 0};
  const float* wr = Wr + (size_t)c0 * NEXP;
#pragma unroll
  for (int i = 0; i < 16; i++) {
    float xv = v[i];
    float4 wl = *(const float4*)(wr + i * 8);
    float4 wh = *(const float4*)(wr + i * 8 + 4);
    p[0] += xv * wl.x; p[1] += xv * wl.y; p[2] += xv * wl.z; p[3] += xv * wl.w;
    p[4] += xv * wh.x; p[5] += xv * wh.y; p[6] += xv * wh.z; p[7] += xv * wh.w;
  }
#pragma unroll
  for (int off = 32; off >= 1; off >>= 1) {
#pragma unroll
    for (int e = 0; e < 8; e++) p[e] += __shfl_xor(p[e], off, 64);
  }
  if (lane == 0) {
    float lg[8];
#pragma unroll
    for (int e = 0; e < 8; e++) lg[e] = p[e] + br[e];
    float v0 = lg[0]; int i0 = 0;
#pragma unroll
    for (int e = 1; e < 8; e++) if (lg[e] > v0) { v0 = lg[e]; i0 = e; }
    float v1 = -3.4e38f; int i1 = 0;
#pragma unroll
    for (int e = 0; e < 8; e++)
      if (e != i0 && lg[e] > v1) { v1 = lg[e]; i1 = e; }
    float ee = __expf(v1 - v0);
    float g0 = 1.0f / (1.0f + ee);
    float g1 = ee / (1.0f + ee);
    int4 rec;
    rec.x = i0; rec.y = i1;
    rec.z = __float_as_int(g0); rec.w = __float_as_int(g1);
    topk[t] = rec;
  }
}

// ---------------- Scatter: block-aggregated slot assignment -----------------
__global__ __launch_bounds__(512) void scatter_kernel(
    const int4* __restrict__ topk, int* __restrict__ counts,
    int* __restrict__ tok, int2* __restrict__ pos) {
  __shared__ int lcnt[NEXP], lbase[NEXP];
  const int tid = threadIdx.x;
  if (tid < NEXP) lcnt[tid] = 0;
  __syncthreads();
  const int t = blockIdx.x * 512 + tid;
  int4 r = topk[t];
  int s0 = atomicAdd(&lcnt[r.x], 1);
  int s1 = atomicAdd(&lcnt[r.y], 1);
  __syncthreads();
  if (tid < NEXP) lbase[tid] = atomicAdd(&counts[tid], lcnt[tid]);
  __syncthreads();
  int p0 = lbase[r.x] + s0;
  int p1 = lbase[r.y] + s1;
  tok[r.x * CAP + p0] = t;
  tok[r.y * CAP + p1] = t;
  int2 pr; pr.x = p0; pr.y = p1;
  pos[t] = pr;
}

// ---------------- Tile-descriptor build + expert offsets (prefix sum) ------
__global__ __launch_bounds__(64) void build_tiles_kernel(
    const int* __restrict__ counts, int* __restrict__ desc,
    int* __restrict__ ntiles, int* __restrict__ offset) {
  if (threadIdx.x == 0) {
    int idx = 0, off = 0;
#pragma unroll
    for (int e = 0; e < NEXP; e++) {
      offset[e] = off;
      off += counts[e];
      int nm = (counts[e] + 127) >> 7;
      for (int i = 0; i < nm; i++) desc[idx++] = (e << 16) | i;
    }
    *ntiles = idx;
  }
}

// ---------------- Routed expert GEMM -> slot-major bf16 ybuf ----------------
// Tile 128x128, two BK=32 stages per barrier (eff. BK=64), 4 waves 2x2.
// LDS exactly 32768B -> 5 blocks/CU. Grid (slot-fast, n-tile) so ~16
// consecutive blocks share one 256KB B-tile (L2 reuse).
__global__ __launch_bounds__(256) void moe_gemm_kernel(
    const unsigned short* __restrict__ xbf, const unsigned short* __restrict__ wt,
    const int* __restrict__ counts, const int* __restrict__ offset,
    const int* __restrict__ tok, const int* __restrict__ desc,
    const int* __restrict__ ntiles, unsigned short* __restrict__ ybuf) {
  const int slot = blockIdx.x;
  if (slot >= *ntiles) return;
  const int dsc = desc[slot];
  const int e = dsc >> 16;
  const int m0 = (dsc & 0xffff) * 128;
  const int cnt = counts[e];
  const int n0 = blockIdx.y * 128;

  __shared__ __align__(16) unsigned short sA0[128 * 32];
  __shared__ __align__(16) unsigned short sB0[128 * 32];
  __shared__ __align__(16) unsigned short sA1[128 * 32];
  __shared__ __align__(16) unsigned short sB1[128 * 32];

  const int tid = threadIdx.x, wave = tid >> 6, lane = tid & 63;

  // staging: wave w stages 16-row groups {w, w+4}; lane i -> row g*16+(i>>2),
  // chunk slot i&3; source chunk XOR-swizzled (2-way LDS aliasing = free).
  const int rA1 = wave * 16 + (lane >> 2);
  const int rA2 = rA1 + 64;
  const int cch = lane & 3;
  const int cg1 = (cch ^ ((rA1 >> 1) & 3)) * 8;  // elements
  const int cg2 = (cch ^ ((rA2 >> 1) & 3)) * 8;
  // per-lane token ids (row clamp to cnt-1 for partial tiles)
  int r1 = m0 + rA1; if (r1 >= cnt) r1 = cnt - 1;
  int r2 = m0 + rA2; if (r2 >= cnt) r2 = cnt - 1;
  const int t1 = tok[e * CAP + r1];
  const int t2 = tok[e * CAP + r2];
  const unsigned short* pA1 = xbf + (size_t)t1 * DM + cg1;
  const unsigned short* pA2 = xbf + (size_t)t2 * DM + cg2;
  const unsigned short* wte = wt + (size_t)e * DM * DM;
  const unsigned short* pB1 = wte + (size_t)(n0 + rA1) * DM + cg1;
  const unsigned short* pB2 = wte + (size_t)(n0 + rA2) * DM + cg2;
  const int lo1 = wave * 512, lo2 = (wave + 4) * 512;  // 1KB per 16-row group

  const int q = lane >> 4, ml = lane & 15;
  const int wm = (wave >> 1) * 64, wn = (wave & 1) * 64;
  int offA[4], offB[4];
#pragma unroll
  for (int i = 0; i < 4; i++) {
    int row = wm + i * 16 + ml;
    offA[i] = row * 32 + (q ^ ((row >> 1) & 3)) * 8;
    int rowb = wn + i * 16 + ml;
    offB[i] = rowb * 32 + (q ^ ((rowb >> 1) & 3)) * 8;
  }

  f32x4 acc[4][4] = {};

  for (int k0 = 0; k0 < DM; k0 += 64) {
    gl_lds16(pA1 + k0, sA0 + lo1);
    gl_lds16(pA2 + k0, sA0 + lo2);
    gl_lds16(pB1 + k0, sB0 + lo1);
    gl_lds16(pB2 + k0, sB0 + lo2);
    gl_lds16(pA1 + k0 + 32, sA1 + lo1);
    gl_lds16(pA2 + k0 + 32, sA1 + lo2);
    gl_lds16(pB1 + k0 + 32, sB1 + lo1);
    gl_lds16(pB2 + k0 + 32, sB1 + lo2);
    __syncthreads();
    bf16x8 af0[4], bf0[4], af1[4], bf1[4];
#pragma unroll
    for (int i = 0; i < 4; i++) {
      af0[i] = *(const bf16x8*)(sA0 + offA[i]);
      bf0[i] = *(const bf16x8*)(sB0 + offB[i]);
      af1[i] = *(const bf16x8*)(sA1 + offA[i]);
      bf1[i] = *(const bf16x8*)(sB1 + offB[i]);
    }
#pragma unroll
    for (int mt = 0; mt < 4; mt++)
#pragma unroll
      for (int nt = 0; nt < 4; nt++)
        acc[mt][nt] = __builtin_amdgcn_mfma_f32_16x16x32_bf16(
            af0[mt], bf0[nt], acc[mt][nt], 0, 0, 0);
#pragma unroll
    for (int mt = 0; mt < 4; mt++)
#pragma unroll
      for (int nt = 0; nt < 4; nt++)
        acc[mt][nt] = __builtin_amdgcn_mfma_f32_16x16x32_bf16(
            af1[mt], bf1[nt], acc[mt][nt], 0, 0, 0);
    __syncthreads();
  }

  // epilogue: plain bf16 stores of raw accumulators (slot-major)
  const int yb = offset[e] + m0;
#pragma unroll
  for (int mt = 0; mt < 4; mt++) {
    int rbase = wm + mt * 16 + q * 4;
#pragma unroll
    for (int r = 0; r < 4; r++) {
      int row = rbase + r;
      if (m0 + row >= cnt) continue;
      unsigned short* yrow = ybuf + (size_t)(yb + row) * DM + n0;
#pragma unroll
      for (int nt = 0; nt < 4; nt++) {
        yrow[wn + nt * 16 + ml] = f2bf(acc[mt][nt][r]);
      }
    }
  }
}

// ---------------- Combine: out[t] = g0*(y0+b[e0]) + g1*(y1+b[e1]) -----------
__global__ __launch_bounds__(256) void combine_kernel(
    const unsigned short* __restrict__ ybuf, const int4* __restrict__ topk,
    const int2* __restrict__ pos, const int* __restrict__ offset,
    const float* __restrict__ bias, float* __restrict__ out) {
  const int t = blockIdx.x;
  const int c = threadIdx.x * 4;
  int4 r = topk[t];
  int2 p = pos[t];
  float g0 = __int_as_float(r.z), g1 = __int_as_float(r.w);
  int s0 = offset[r.x] + p.x;
  int s1 = offset[r.y] + p.y;
  ushort4 ya = *(const ushort4*)(ybuf + (size_t)s0 * DM + c);
  ushort4 yb = *(const ushort4*)(ybuf + (size_t)s1 * DM + c);
  float4 b0 = *(const float4*)(bias + (size_t)r.x * DM + c);
  float4 b1 = *(const float4*)(bias + (size_t)r.y * DM + c);
  float4 o;
  o.x = g0 * (bf2f(ya.x) + b0.x) + g1 * (bf2f(yb.x) + b1.x);
  o.y = g0 * (bf2f(ya.y) + b0.y) + g1 * (bf2f(yb.y) + b1.y);
  o.z = g0 * (bf2f(ya.z) + b0.z) + g1 * (bf2f(yb.z) + b1.z);
  o.w = g0 * (bf2f(ya.w) + b0.w) + g1 * (bf2f(yb.w) + b1.w);
  *(float4*)(out + (size_t)t * DM + c) = o;
}

extern "C" void kernel_launch(void* const* d_in, const int* in_sizes, int n_in,
                              void* d_out, int out_size, void* d_ws, size_t ws_size,
                              hipStream_t stream) {
  const float* x  = (const float*)d_in[0];
  const float* Wr = (const float*)d_in[1];
  const float* br = (const float*)d_in[2];
  const float* W  = (const float*)d_in[3];
  const float* b  = (const float*)d_in[4];
  float* out = (float*)d_out;

  // workspace layout (~65.5 MB)
  char* ws = (char*)d_ws;
  unsigned short* xbf  = (unsigned short*)ws;                       // 16 MB
  unsigned short* wt   = (unsigned short*)(ws + (16u << 20));       // 16 MB
  unsigned short* ybuf = (unsigned short*)(ws + (32u << 20));       // 32 MB
  char* ctrl = ws + (64u << 20);
  int*   counts = (int*)ctrl;                                       // 32 B
  int*   ntiles = (int*)(ctrl + 64);                                // 4 B
  int*   offset = (int*)(ctrl + 128);                               // 32 B
  int*   desc   = (int*)(ctrl + 256);                               // 544 B
  int*   tok    = (int*)(ctrl + 4096);                              // 256 KB
  int2*  pos    = (int2*)(ctrl + 4096 + (256u << 10));              // 64 KB
  int4*  topk   = (int4*)(ctrl + 4096 + (320u << 10));              // 128 KB

  hipMemsetAsync(counts, 0, 128, stream);  // counts + ntiles

  transpose_w_kernel<<<dim3(16, 4, 8), 256, 0, stream>>>(W, wt);
  router_compute_kernel<<<NTOK / 4, 256, 0, stream>>>(x, Wr, br, xbf, topk);
  scatter_kernel<<<16, 512, 0, stream>>>(topk, counts, tok, pos);
  build_tiles_kernel<<<1, 64, 0, stream>>>(counts, desc, ntiles, offset);
  moe_gemm_kernel<<<dim3(MAXT, 8), 256, 0, stream>>>(
      xbf, wt, counts, offset, tok, desc, ntiles, ybuf);
  combine_kernel<<<NTOK, 256, 0, stream>>>(ybuf, topk, pos, offset, b, out);
}

// Round 6
// 215.084 us; speedup vs baseline: 1.0000x; 1.0000x over previous
//
#include <hip/hip_runtime.h>
#include <hip/hip_bf16.h>

// MoE: N=8192 tokens, D=1024, E=8 experts, top-2 routing.
// Inputs (fp32): x[8192,1024], Wr[1024,8], br[8], W[8,1024,1024], b[8,1024]
// Output (fp32): out[8192,1024]
//
// R1: block-aggregated scatter. R2: dense tile list. R3: split-K regressed.
// R4: atomic-free epilogue (bf16 ybuf + combine), eff. BK=64 -> 59us GEMM.
// R5: grid reorder regressed (XCD pinning); LDS shrink didn't lift occupancy.
// R6: revert GEMM grid to R4 order; cut 7 dispatches -> 4:
//     fused(transpose || router || zero-counts), scatter, gemm (inline tile
//     walk, no build_tiles), combine (wave/token, inline offsets).

#define NTOK 8192
#define DM   1024
#define NEXP 8
#define CAP  8192    // per-expert slot capacity (worst case)
#define MAXT 136     // max total m-tiles

typedef __attribute__((ext_vector_type(8))) short bf16x8;
typedef __attribute__((ext_vector_type(4))) float f32x4;

__device__ __forceinline__ unsigned short f2bf(float f) {
  unsigned u = __float_as_uint(f);
  unsigned r = (u + 0x7fffu + ((u >> 16) & 1u)) >> 16;
  return (unsigned short)r;
}
__device__ __forceinline__ float bf2f(unsigned short s) {
  return __uint_as_float(((unsigned)s) << 16);
}

__device__ __forceinline__ void gl_lds16(const void* g, void* l) {
  __builtin_amdgcn_global_load_lds(
      (const __attribute__((address_space(1))) unsigned int*)g,
      (__attribute__((address_space(3))) unsigned int*)l, 16, 0, 0);
}

// ---------------- Fused pre-pass: W-transpose blocks + router blocks --------
// Blocks [0,1024): transpose+cast 64h x 128d tile of one expert.
// Blocks [1024,3072): router for 4 tokens (wave per token) + x->bf16 cast.
// Block 0 additionally zeroes counts[] (safe: scatter is a later dispatch).
__global__ __launch_bounds__(256) void prepass_kernel(
    const float* __restrict__ W, unsigned short* __restrict__ Wt,
    const float* __restrict__ x, const float* __restrict__ Wr,
    const float* __restrict__ br, unsigned short* __restrict__ xbf,
    int4* __restrict__ topk, int* __restrict__ counts) {
  __shared__ unsigned short L[64 * 132];  // pad 132: 264B row, 8B-aligned
  const int bx = blockIdx.x;
  const int tid = threadIdx.x;

  if (bx == 0 && tid < NEXP) counts[tid] = 0;

  if (bx < 1024) {
    // ---- transpose: e = bx&7, dblk = (bx>>3)&7, hblk = bx>>6
    const int e = bx & 7;
    const int d0 = ((bx >> 3) & 7) * 128;
    const int h0 = (bx >> 6) * 64;
    const float* Ws = W + (size_t)e * DM * DM;
    unsigned short* Wd = Wt + (size_t)e * DM * DM;
    const int hh = (tid & 15) * 4;  // 0..60
    const int dr = tid >> 4;        // 0..15
#pragma unroll
    for (int it = 0; it < 8; it++) {
      int dd = it * 16 + dr;
      float4 v = *(const float4*)(Ws + (size_t)(d0 + dd) * DM + h0 + hh);
      L[(hh + 0) * 132 + dd] = f2bf(v.x);
      L[(hh + 1) * 132 + dd] = f2bf(v.y);
      L[(hh + 2) * 132 + dd] = f2bf(v.z);
      L[(hh + 3) * 132 + dd] = f2bf(v.w);
    }
    __syncthreads();
    const int dc = (tid & 31) * 4;  // 0..124
    const int hw = tid >> 5;        // 0..7
#pragma unroll
    for (int it = 0; it < 8; it++) {
      int hr = it * 8 + hw;
      ushort4 o = *(const ushort4*)(&L[hr * 132 + dc]);
      *(ushort4*)(Wd + (size_t)(h0 + hr) * DM + d0 + dc) = o;
    }
    return;
  }

  // ---- router: wave per token
  const int wave = tid >> 6, lane = tid & 63;
  const int t = (bx - 1024) * 4 + wave;
  const int c0 = lane * 16;
  const float* xr = x + (size_t)t * DM + c0;

  float v[16];
#pragma unroll
  for (int i = 0; i < 4; i++) {
    float4 f = *(const float4*)(xr + i * 4);
    v[i * 4 + 0] = f.x; v[i * 4 + 1] = f.y; v[i * 4 + 2] = f.z; v[i * 4 + 3] = f.w;
  }
  union { unsigned short s[8]; uint4 q; } pk;
#pragma unroll
  for (int half = 0; half < 2; half++) {
#pragma unroll
    for (int i = 0; i < 8; i++) pk.s[i] = f2bf(v[half * 8 + i]);
    *(uint4*)(xbf + (size_t)t * DM + c0 + half * 8) = pk.q;
  }
  float p[8] = {0, 0, 0, 0, 0, 0, 0, 0};
  const float* wr = Wr + (size_t)c0 * NEXP;
#pragma unroll
  for (int i = 0; i < 16; i++) {
    float xv = v[i];
    float4 wl = *(const float4*)(wr + i * 8);
    float4 wh = *(const float4*)(wr + i * 8 + 4);
    p[0] += xv * wl.x; p[1] += xv * wl.y; p[2] += xv * wl.z; p[3] += xv * wl.w;
    p[4] += xv * wh.x; p[5] += xv * wh.y; p[6] += xv * wh.z; p[7] += xv * wh.w;
  }
#pragma unroll
  for (int off = 32; off >= 1; off >>= 1) {
#pragma unroll
    for (int e = 0; e < 8; e++) p[e] += __shfl_xor(p[e], off, 64);
  }
  if (lane == 0) {
    float lg[8];
#pragma unroll
    for (int e = 0; e < 8; e++) lg[e] = p[e] + br[e];
    float v0 = lg[0]; int i0 = 0;
#pragma unroll
    for (int e = 1; e < 8; e++) if (lg[e] > v0) { v0 = lg[e]; i0 = e; }
    float v1 = -3.4e38f; int i1 = 0;
#pragma unroll
    for (int e = 0; e < 8; e++)
      if (e != i0 && lg[e] > v1) { v1 = lg[e]; i1 = e; }
    float ee = __expf(v1 - v0);
    float g0 = 1.0f / (1.0f + ee);
    float g1 = ee / (1.0f + ee);
    int4 rec;
    rec.x = i0; rec.y = i1;
    rec.z = __float_as_int(g0); rec.w = __float_as_int(g1);
    topk[t] = rec;
  }
}

// ---------------- Scatter: block-aggregated slot assignment -----------------
__global__ __launch_bounds__(512) void scatter_kernel(
    const int4* __restrict__ topk, int* __restrict__ counts,
    int* __restrict__ tok, int2* __restrict__ pos) {
  __shared__ int lcnt[NEXP], lbase[NEXP];
  const int tid = threadIdx.x;
  if (tid < NEXP) lcnt[tid] = 0;
  __syncthreads();
  const int t = blockIdx.x * 512 + tid;
  int4 r = topk[t];
  int s0 = atomicAdd(&lcnt[r.x], 1);
  int s1 = atomicAdd(&lcnt[r.y], 1);
  __syncthreads();
  if (tid < NEXP) lbase[tid] = atomicAdd(&counts[tid], lcnt[tid]);
  __syncthreads();
  int p0 = lbase[r.x] + s0;
  int p1 = lbase[r.y] + s1;
  tok[r.x * CAP + p0] = t;
  tok[r.y * CAP + p1] = t;
  int2 pr; pr.x = p0; pr.y = p1;
  pos[t] = pr;
}

// ---------------- Routed expert GEMM -> slot-major bf16 ybuf ----------------
// Tile 128x128, two BK=32 stages per barrier (eff. BK=64), 4 waves 2x2.
// Grid (8 n-tiles fast, MAXT slots): XCD = n-tile -> per-XCD B-tile locality
// (R4-proven). Slot->(e,m0,offset) walked inline from counts (no desc).
__global__ __launch_bounds__(256) void moe_gemm_kernel(
    const unsigned short* __restrict__ xbf, const unsigned short* __restrict__ wt,
    const int* __restrict__ counts, const int* __restrict__ tok,
    unsigned short* __restrict__ ybuf) {
  const int slot = blockIdx.y;
  // inline tile walk: find expert e with slot in its m-tile range
  int e = 0, m0 = 0, yb0 = 0, cnt = 0;
  {
    int tacc = 0, oacc = 0, found = 0;
#pragma unroll
    for (int ee = 0; ee < NEXP; ee++) {
      int c = counts[ee];
      int nm = (c + 127) >> 7;
      if (!found && slot < tacc + nm) {
        e = ee; m0 = (slot - tacc) * 128; yb0 = oacc; cnt = c; found = 1;
      }
      tacc += nm; oacc += c;
    }
    if (!found) return;
  }
  const int n0 = blockIdx.x * 128;

  __shared__ __align__(16) unsigned short sA0[128 * 32];
  __shared__ __align__(16) unsigned short sB0[128 * 32];
  __shared__ __align__(16) unsigned short sA1[128 * 32];
  __shared__ __align__(16) unsigned short sB1[128 * 32];

  const int tid = threadIdx.x, wave = tid >> 6, lane = tid & 63;

  // staging: wave w stages 16-row groups {w, w+4}; lane i -> row g*16+(i>>2),
  // chunk slot i&3; source chunk XOR-swizzled (2-way LDS aliasing = free).
  const int rA1 = wave * 16 + (lane >> 2);
  const int rA2 = rA1 + 64;
  const int cch = lane & 3;
  const int cg1 = (cch ^ ((rA1 >> 1) & 3)) * 8;  // elements
  const int cg2 = (cch ^ ((rA2 >> 1) & 3)) * 8;
  int r1 = m0 + rA1; if (r1 >= cnt) r1 = cnt - 1;
  int r2 = m0 + rA2; if (r2 >= cnt) r2 = cnt - 1;
  const int t1 = tok[e * CAP + r1];
  const int t2 = tok[e * CAP + r2];
  const unsigned short* pA1 = xbf + (size_t)t1 * DM + cg1;
  const unsigned short* pA2 = xbf + (size_t)t2 * DM + cg2;
  const unsigned short* wte = wt + (size_t)e * DM * DM;
  const unsigned short* pB1 = wte + (size_t)(n0 + rA1) * DM + cg1;
  const unsigned short* pB2 = wte + (size_t)(n0 + rA2) * DM + cg2;
  const int lo1 = wave * 512, lo2 = (wave + 4) * 512;  // 1KB per 16-row group

  const int q = lane >> 4, ml = lane & 15;
  const int wm = (wave >> 1) * 64, wn = (wave & 1) * 64;
  int offA[4], offB[4];
#pragma unroll
  for (int i = 0; i < 4; i++) {
    int row = wm + i * 16 + ml;
    offA[i] = row * 32 + (q ^ ((row >> 1) & 3)) * 8;
    int rowb = wn + i * 16 + ml;
    offB[i] = rowb * 32 + (q ^ ((rowb >> 1) & 3)) * 8;
  }

  f32x4 acc[4][4] = {};

  for (int k0 = 0; k0 < DM; k0 += 64) {
    gl_lds16(pA1 + k0, sA0 + lo1);
    gl_lds16(pA2 + k0, sA0 + lo2);
    gl_lds16(pB1 + k0, sB0 + lo1);
    gl_lds16(pB2 + k0, sB0 + lo2);
    gl_lds16(pA1 + k0 + 32, sA1 + lo1);
    gl_lds16(pA2 + k0 + 32, sA1 + lo2);
    gl_lds16(pB1 + k0 + 32, sB1 + lo1);
    gl_lds16(pB2 + k0 + 32, sB1 + lo2);
    __syncthreads();
    bf16x8 af0[4], bf0[4], af1[4], bf1[4];
#pragma unroll
    for (int i = 0; i < 4; i++) {
      af0[i] = *(const bf16x8*)(sA0 + offA[i]);
      bf0[i] = *(const bf16x8*)(sB0 + offB[i]);
      af1[i] = *(const bf16x8*)(sA1 + offA[i]);
      bf1[i] = *(const bf16x8*)(sB1 + offB[i]);
    }
#pragma unroll
    for (int mt = 0; mt < 4; mt++)
#pragma unroll
      for (int nt = 0; nt < 4; nt++)
        acc[mt][nt] = __builtin_amdgcn_mfma_f32_16x16x32_bf16(
            af0[mt], bf0[nt], acc[mt][nt], 0, 0, 0);
#pragma unroll
    for (int mt = 0; mt < 4; mt++)
#pragma unroll
      for (int nt = 0; nt < 4; nt++)
        acc[mt][nt] = __builtin_amdgcn_mfma_f32_16x16x32_bf16(
            af1[mt], bf1[nt], acc[mt][nt], 0, 0, 0);
    __syncthreads();
  }

  // epilogue: plain bf16 stores of raw accumulators (slot-major)
  const int yb = yb0 + m0;
#pragma unroll
  for (int mt = 0; mt < 4; mt++) {
    int rbase = wm + mt * 16 + q * 4;
#pragma unroll
    for (int r = 0; r < 4; r++) {
      int row = rbase + r;
      if (m0 + row >= cnt) continue;
      unsigned short* yrow = ybuf + (size_t)(yb + row) * DM + n0;
#pragma unroll
      for (int nt = 0; nt < 4; nt++) {
        yrow[wn + nt * 16 + ml] = f2bf(acc[mt][nt][r]);
      }
    }
  }
}

// ---------------- Combine: out[t] = g0*(y0+b[e0]) + g1*(y1+b[e1]) -----------
// Wave per token (2048 blocks); expert offsets prefix-summed inline.
__global__ __launch_bounds__(256) void combine_kernel(
    const unsigned short* __restrict__ ybuf, const int4* __restrict__ topk,
    const int2* __restrict__ pos, const int* __restrict__ counts,
    const float* __restrict__ bias, float* __restrict__ out) {
  const int tid = threadIdx.x;
  const int wave = tid >> 6, lane = tid & 63;
  const int t = blockIdx.x * 4 + wave;
  int4 r = topk[t];
  int2 p = pos[t];
  // inline expert offsets
  int off0 = 0, off1 = 0;
#pragma unroll
  for (int e = 0; e < NEXP; e++) {
    int c = counts[e];
    if (e < r.x) off0 += c;
    if (e < r.y) off1 += c;
  }
  float g0 = __int_as_float(r.z), g1 = __int_as_float(r.w);
  const unsigned short* y0 = ybuf + (size_t)(off0 + p.x) * DM + lane * 16;
  const unsigned short* y1 = ybuf + (size_t)(off1 + p.y) * DM + lane * 16;
  const float* b0 = bias + (size_t)r.x * DM + lane * 16;
  const float* b1 = bias + (size_t)r.y * DM + lane * 16;
  float* orow = out + (size_t)t * DM + lane * 16;
  union { ushort4 u4; unsigned short s[4]; } ya, yb;
#pragma unroll
  for (int j = 0; j < 4; j++) {
    ya.u4 = *(const ushort4*)(y0 + j * 4);
    yb.u4 = *(const ushort4*)(y1 + j * 4);
    float4 c0 = *(const float4*)(b0 + j * 4);
    float4 c1 = *(const float4*)(b1 + j * 4);
    float4 o;
    o.x = g0 * (bf2f(ya.s[0]) + c0.x) + g1 * (bf2f(yb.s[0]) + c1.x);
    o.y = g0 * (bf2f(ya.s[1]) + c0.y) + g1 * (bf2f(yb.s[1]) + c1.y);
    o.z = g0 * (bf2f(ya.s[2]) + c0.z) + g1 * (bf2f(yb.s[2]) + c1.z);
    o.w = g0 * (bf2f(ya.s[3]) + c0.w) + g1 * (bf2f(yb.s[3]) + c1.w);
    *(float4*)(orow + j * 4) = o;
  }
}

extern "C" void kernel_launch(void* const* d_in, const int* in_sizes, int n_in,
                              void* d_out, int out_size, void* d_ws, size_t ws_size,
                              hipStream_t stream) {
  const float* x  = (const float*)d_in[0];
  const float* Wr = (const float*)d_in[1];
  const float* br = (const float*)d_in[2];
  const float* W  = (const float*)d_in[3];
  const float* b  = (const float*)d_in[4];
  float* out = (float*)d_out;

  // workspace layout (~65.5 MB)
  char* ws = (char*)d_ws;
  unsigned short* xbf  = (unsigned short*)ws;                       // 16 MB
  unsigned short* wt   = (unsigned short*)(ws + (16u << 20));       // 16 MB
  unsigned short* ybuf = (unsigned short*)(ws + (32u << 20));       // 32 MB
  char* ctrl = ws + (64u << 20);
  int*   counts = (int*)ctrl;                                       // 32 B
  int*   tok    = (int*)(ctrl + 4096);                              // 256 KB
  int2*  pos    = (int2*)(ctrl + 4096 + (256u << 10));              // 64 KB
  int4*  topk   = (int4*)(ctrl + 4096 + (320u << 10));              // 128 KB

  prepass_kernel<<<1024 + NTOK / 4, 256, 0, stream>>>(
      W, wt, x, Wr, br, xbf, topk, counts);
  scatter_kernel<<<16, 512, 0, stream>>>(topk, counts, tok, pos);
  moe_gemm_kernel<<<dim3(8, MAXT), 256, 0, stream>>>(
      xbf, wt, counts, tok, ybuf);
  combine_kernel<<<NTOK / 4, 256, 0, stream>>>(
      ybuf, topk, pos, counts, b, out);
}